// Round 1
// baseline (762.300 us; speedup 1.0000x reference)
//
#include <hip/hip_runtime.h>

#define NROWS      100000
#define NUM_CATES  100000
#define NUM_SCENES 5001
#define MAX_NGH    16
#define MAX_SCENES 10
#define DIM        64
#define EPSF       1e-10f

// ---------------- kernel 1: row_sum[i] = sum_k scene_emb[cate_scene_pad[i,k]] ----------------
__global__ __launch_bounds__(256) void rowsum_kernel(
    const float* __restrict__ scene_emb,   // [NUM_SCENES, 64]
    const int*   __restrict__ csp,         // [NROWS, 10]
    float*       __restrict__ rowsum)      // [NROWS, 64] (workspace)
{
    const int wave = threadIdx.x >> 6;
    const int lane = threadIdx.x & 63;
    const int row  = blockIdx.x * 4 + wave;           // NROWS % 4 == 0, grid exact
    const int* p = csp + row * MAX_SCENES;
    float s = 0.f;
#pragma unroll
    for (int k = 0; k < MAX_SCENES; ++k) {
        int idx = p[k];                               // wave-uniform -> scalar load
        s += scene_emb[idx * DIM + lane];             // 256B coalesced gather
    }
    rowsum[row * DIM + lane] = s;
}

// ---------------- kernel 2: similarity softmax + aggregation + dense + ELU ----------------
__global__ __launch_bounds__(256) void main_kernel(
    const float* __restrict__ cate_emb,    // [NUM_CATES, 64]
    const int*   __restrict__ ccp,         // [NROWS, 16]
    const float* __restrict__ W,           // [64, 128] row-major
    const float* __restrict__ bias,        // [64]
    const float* __restrict__ rowsum,      // [NROWS, 64]
    float*       __restrict__ out)         // [NROWS, 64]
{
    __shared__ float Wt[128 * 64];         // Wt[k*64 + d]  (transposed: bank = d%32, 2-way free)
    __shared__ float h[4][128];

    const int tid  = threadIdx.x;
    const int wave = tid >> 6;
    const int lane = tid & 63;
    const int row  = blockIdx.x * 4 + wave;

    // Stage W transposed into LDS (coalesced global read).
    for (int i = tid; i < 64 * 128; i += 256) {
        int d = i >> 7, k = i & 127;
        Wt[k * 64 + d] = W[i];
    }

    // s_i = row_sum[row]
    float s = rowsum[row * DIM + lane];
    float ns = s * s;
#pragma unroll
    for (int off = 32; off > 0; off >>= 1) ns += __shfl_xor(ns, off);
    ns += EPSF;                                       // (||s||^2 + EPS)

    const int* prow = ccp + row * MAX_NGH;
    float miu[1 + MAX_NGH];
    int   idx[1 + MAX_NGH];
    float summiu = 0.f;

#pragma unroll
    for (int j = 0; j < 1 + MAX_NGH; ++j) {
        int id = (j == 0) ? row : prow[j - 1];        // wave-uniform
        idx[j] = id;
        bool m = id < (NUM_CATES - 1);
        float r = rowsum[id * DIM + lane];            // 256B coalesced gather
        float dot = s * r;
        float rr  = r * r;
#pragma unroll
        for (int off = 32; off > 0; off >>= 1) {      // two interleaved butterflies
            dot += __shfl_xor(dot, off);
            rr  += __shfl_xor(rr,  off);
        }
        float sim = m ? dot / (ns * (rr + EPSF)) : 0.f;
        float mu  = m ? __expf(sim) : 0.f;            // exp(0)*0 for masked -> 0 either way
        miu[j] = mu;
        summiu += mu;
    }

    const float inv = 1.f / (summiu + EPSF);
    float agg = 0.f;
#pragma unroll
    for (int j = 0; j < 1 + MAX_NGH; ++j) {
        agg = fmaf(miu[j] * inv, cate_emb[idx[j] * DIM + lane], agg);
    }

    // h = [s, agg]; out = elu(W @ h + b)
    h[wave][lane]      = s;
    h[wave][64 + lane] = agg;
    __syncthreads();                                  // covers Wt staging + h writes

    float acc = bias[lane];
#pragma unroll 8
    for (int k = 0; k < 128; ++k) {
        acc = fmaf(Wt[k * 64 + lane], h[wave][k], acc);  // h read = LDS broadcast (free)
    }
    out[row * DIM + lane] = acc > 0.f ? acc : (__expf(acc) - 1.f);
}

extern "C" void kernel_launch(void* const* d_in, const int* in_sizes, int n_in,
                              void* d_out, int out_size, void* d_ws, size_t ws_size,
                              hipStream_t stream) {
    // setup_inputs order:
    // 0 cids(int32), 1 cate_emb_w(f32), 2 scene_emb_w(f32),
    // 3 cate_scene_pad(int32), 4 c_cate_pad(int32), 5 agg_W(f32), 6 agg_b(f32)
    const float* cate_emb  = (const float*)d_in[1];
    const float* scene_emb = (const float*)d_in[2];
    const int*   csp       = (const int*)d_in[3];
    const int*   ccp       = (const int*)d_in[4];
    const float* W         = (const float*)d_in[5];
    const float* bias      = (const float*)d_in[6];

    float* rowsum = (float*)d_ws;                     // 100000*64*4 = 25.6 MB scratch
    float* out    = (float*)d_out;

    const int blocks = NROWS / 4;                     // 25000, exact
    rowsum_kernel<<<blocks, 256, 0, stream>>>(scene_emb, csp, rowsum);
    main_kernel  <<<blocks, 256, 0, stream>>>(cate_emb, ccp, W, bias, rowsum, out);
}

// Round 2
// 245.083 us; speedup vs baseline: 3.1104x; 3.1104x over previous
//
#include <hip/hip_runtime.h>

#define NROWS      100000
#define NUM_CATES  100000
#define NUM_SCENES 5001
#define MAX_NGH    16
#define MAX_SCENES 10
#define DIM        64
#define EPSF       1e-10f

#define WT_STRIDE  68          // 128 k-rows of 64 d + 4 pad floats (keeps 16B align, banks spread)
#define H_STRIDE4  33          // h row stride in float4 (132 floats): 4 group rows hit distinct banks

typedef float4 f4;

// ---------------- kernel 0: one-time transpose W[64][128] -> Wt_g[k*68 + d] ----------------
__global__ __launch_bounds__(512) void prep_kernel(
    const float* __restrict__ W, float* __restrict__ Wtg)
{
    int i = blockIdx.x * 512 + threadIdx.x;          // 8192 elements
    if (i < DIM * 2 * DIM) {
        int d = i >> 7, k = i & 127;
        Wtg[k * WT_STRIDE + d] = W[i];               // scattered 4B writes, 32KB once: negligible
    }
}

// ---------------- kernel 1: row_sum[i] = sum_k scene_emb[cate_scene_pad[i,k]] ----------------
__global__ __launch_bounds__(256) void rowsum_kernel(
    const float* __restrict__ scene_emb,   // [NUM_SCENES, 64]
    const int*   __restrict__ csp,         // [NROWS, 10]
    float*       __restrict__ rowsum)      // [NROWS, 64]
{
    const int tid  = threadIdx.x;
    const int lane = tid & 63;
    const int l16  = lane & 15;
    const int row  = blockIdx.x * 16 + (tid >> 6) * 4 + (lane >> 4);  // 16 rows/block

    const f4* scene4 = (const f4*)scene_emb;
    // lanes 0..9 of each 16-group hold this row's 10 scene ids (clamp avoids OOB on last row)
    int sidx = csp[row * MAX_SCENES + (l16 < 9 ? l16 : 9)];

    f4 s = {0.f, 0.f, 0.f, 0.f};
#pragma unroll
    for (int k = 0; k < MAX_SCENES; ++k) {
        int id = __shfl(sidx, k, 16);                // broadcast within 16-lane group
        f4 v = scene4[id * 16 + l16];                // 256B contiguous per group
        s.x += v.x; s.y += v.y; s.z += v.z; s.w += v.w;
    }
    ((f4*)rowsum)[row * 16 + l16] = s;
}

__device__ __forceinline__ float reduce16(float v) {
#pragma unroll
    for (int off = 1; off < 16; off <<= 1) v += __shfl_xor(v, off);
    return v;
}

// ---------------- kernel 2: sim softmax + aggregation + dense + ELU ----------------
__global__ __launch_bounds__(512) void main_kernel(
    const float* __restrict__ cate_emb,    // [NUM_CATES, 64]
    const int*   __restrict__ ccp,         // [NROWS, 16]
    const float* __restrict__ Wtg,         // [128, 68] transposed W (workspace)
    const float* __restrict__ bias,        // [64]
    const float* __restrict__ rowsum,      // [NROWS, 64]
    float*       __restrict__ out)         // [NROWS, 64]
{
    __shared__ float Wt[128 * WT_STRIDE];            // 34816 B
    __shared__ f4    hsh[32 * H_STRIDE4];            // 16896 B; h[r][k], padded rows

    const int tid  = threadIdx.x;
    const int lane = tid & 63;
    const int l16  = lane & 15;
    const int rl   = (tid >> 6) * 4 + (lane >> 4);   // local row 0..31
    const int row  = blockIdx.x * 32 + rl;

    // Stage transposed W: straight copy, consecutive addresses -> conflict-free
    for (int i = tid; i < 128 * WT_STRIDE; i += 512) Wt[i] = Wtg[i];

    const f4* rowsum4 = (const f4*)rowsum;
    const f4* cate4   = (const f4*)cate_emb;

    // s = row_sum[row], ns = ||s||^2 + eps
    f4 s = rowsum4[row * 16 + l16];
    float ns = reduce16(s.x * s.x + s.y * s.y + s.z * s.z + s.w * s.w) + EPSF;

    // all 16 neighbor ids of this row, one per lane of the group
    int nidx = ccp[row * MAX_NGH + l16];

    float miu[1 + MAX_NGH];
    float summiu = 0.f;
#pragma unroll
    for (int j = 0; j < 1 + MAX_NGH; ++j) {
        int id = (j == 0) ? row : __shfl(nidx, j - 1, 16);
        bool m = id < (NUM_CATES - 1);
        f4 r = rowsum4[id * 16 + l16];               // 256B contiguous gather per group
        float dot = s.x * r.x + s.y * r.y + s.z * r.z + s.w * r.w;
        float rr  = r.x * r.x + r.y * r.y + r.z * r.z + r.w * r.w;
#pragma unroll
        for (int off = 1; off < 16; off <<= 1) {     // two interleaved butterflies
            dot += __shfl_xor(dot, off);
            rr  += __shfl_xor(rr,  off);
        }
        float mu = m ? __expf(dot / (ns * (rr + EPSF))) : 0.f;
        miu[j] = mu;
        summiu += mu;
    }

    const float inv = 1.f / (summiu + EPSF);
    f4 agg = {0.f, 0.f, 0.f, 0.f};
#pragma unroll
    for (int j = 0; j < 1 + MAX_NGH; ++j) {
        int id = (j == 0) ? row : __shfl(nidx, j - 1, 16);
        float w = miu[j] * inv;
        f4 c = cate4[id * 16 + l16];
        agg.x = fmaf(w, c.x, agg.x);
        agg.y = fmaf(w, c.y, agg.y);
        agg.z = fmaf(w, c.z, agg.z);
        agg.w = fmaf(w, c.w, agg.w);
    }

    // h = [s | agg] into LDS (padded row stride: the 4 group-rows land on distinct banks)
    hsh[rl * H_STRIDE4 + l16]      = s;
    hsh[rl * H_STRIDE4 + 16 + l16] = agg;
    __syncthreads();                                 // covers Wt staging + h writes

    // out[d] = elu( sum_k Wt[k][d] * h[k] + b[d] ),  lane owns d = 4*l16 .. 4*l16+3
    const f4* bias4 = (const f4*)bias;
    f4 acc = bias4[l16];
#pragma unroll 8
    for (int k4 = 0; k4 < 32; ++k4) {
        f4 hv = hsh[rl * H_STRIDE4 + k4];            // b128, 4 distinct banks across groups
        const float* wp = &Wt[(k4 * 4) * WT_STRIDE + 4 * l16];
        f4 w0 = *(const f4*)(wp);
        f4 w1 = *(const f4*)(wp + WT_STRIDE);
        f4 w2 = *(const f4*)(wp + 2 * WT_STRIDE);
        f4 w3 = *(const f4*)(wp + 3 * WT_STRIDE);
        acc.x = fmaf(hv.x, w0.x, acc.x); acc.y = fmaf(hv.x, w0.y, acc.y);
        acc.z = fmaf(hv.x, w0.z, acc.z); acc.w = fmaf(hv.x, w0.w, acc.w);
        acc.x = fmaf(hv.y, w1.x, acc.x); acc.y = fmaf(hv.y, w1.y, acc.y);
        acc.z = fmaf(hv.y, w1.z, acc.z); acc.w = fmaf(hv.y, w1.w, acc.w);
        acc.x = fmaf(hv.z, w2.x, acc.x); acc.y = fmaf(hv.z, w2.y, acc.y);
        acc.z = fmaf(hv.z, w2.z, acc.z); acc.w = fmaf(hv.z, w2.w, acc.w);
        acc.x = fmaf(hv.w, w3.x, acc.x); acc.y = fmaf(hv.w, w3.y, acc.y);
        acc.z = fmaf(hv.w, w3.z, acc.z); acc.w = fmaf(hv.w, w3.w, acc.w);
    }

    f4 o;
    o.x = acc.x > 0.f ? acc.x : (__expf(acc.x) - 1.f);
    o.y = acc.y > 0.f ? acc.y : (__expf(acc.y) - 1.f);
    o.z = acc.z > 0.f ? acc.z : (__expf(acc.z) - 1.f);
    o.w = acc.w > 0.f ? acc.w : (__expf(acc.w) - 1.f);
    ((f4*)out)[row * 16 + l16] = o;
}

extern "C" void kernel_launch(void* const* d_in, const int* in_sizes, int n_in,
                              void* d_out, int out_size, void* d_ws, size_t ws_size,
                              hipStream_t stream) {
    const float* cate_emb  = (const float*)d_in[1];
    const float* scene_emb = (const float*)d_in[2];
    const int*   csp       = (const int*)d_in[3];
    const int*   ccp       = (const int*)d_in[4];
    const float* W         = (const float*)d_in[5];
    const float* bias      = (const float*)d_in[6];

    float* Wtg    = (float*)d_ws;                          // 128*68*4 = 34816 B
    float* rowsum = (float*)((char*)d_ws + 128 * WT_STRIDE * 4);  // 25.6 MB, 16B-aligned
    float* out    = (float*)d_out;

    prep_kernel  <<<16,            512, 0, stream>>>(W, Wtg);
    rowsum_kernel<<<NROWS / 16,    256, 0, stream>>>(scene_emb, csp, rowsum);
    main_kernel  <<<NROWS / 32,    512, 0, stream>>>(cate_emb, ccp, Wtg, bias, rowsum, out);
}

// Round 3
// 182.213 us; speedup vs baseline: 4.1836x; 1.3450x over previous
//
#include <hip/hip_runtime.h>

#define NROWS      100000
#define NUM_CATES  100000
#define NUM_SCENES 5001
#define MAX_NGH    16
#define MAX_SCENES 10
#define DIM        64
#define EPSF       1e-10f

typedef float4 f4;
typedef _Float16 h2 __attribute__((ext_vector_type(2)));
typedef _Float16 h4 __attribute__((ext_vector_type(4)));

#if __has_builtin(__builtin_amdgcn_fdot2)
#define FDOT2(a, b, c) __builtin_amdgcn_fdot2((a), (b), (c), false)
#else
#define FDOT2(a, b, c) (fmaf((float)(a).x, (float)(b).x, fmaf((float)(a).y, (float)(b).y, (c))))
#endif

#if __has_builtin(__builtin_amdgcn_rcpf)
#define FRCP(x) __builtin_amdgcn_rcpf(x)
#else
#define FRCP(x) (1.0f / (x))
#endif

__device__ __forceinline__ h2 bc2(unsigned int u) { return __builtin_bit_cast(h2, u); }

// ---- prep: block 0 packs W[64][128] -> Wt2g[k2*64+d] = half2(W[d][2k2],W[d][2k2+1]);
//      blocks 1..3125 convert cate_emb f32 -> h4 ----
__global__ __launch_bounds__(512) void prep_kernel(
    const float* __restrict__ W, const float* __restrict__ cate_emb,
    unsigned int* __restrict__ Wt2g, h4* __restrict__ cate_h)
{
    const int b = blockIdx.x, tid = threadIdx.x;
    if (b == 0) {
#pragma unroll
        for (int e = tid; e < 64 * 64; e += 512) {
            int k2 = e >> 6, d = e & 63;
            h2 p = {(_Float16)W[d * 128 + 2 * k2], (_Float16)W[d * 128 + 2 * k2 + 1]};
            Wt2g[e] = __builtin_bit_cast(unsigned int, p);
        }
    } else {
        int i = (b - 1) * 512 + tid;                  // 3125*512 = 1,600,000 f4 exact
        f4 v = ((const f4*)cate_emb)[i];
        h4 o = {(_Float16)v.x, (_Float16)v.y, (_Float16)v.z, (_Float16)v.w};
        cate_h[i] = o;
    }
}

__device__ __forceinline__ float reduce16(float v) {
#pragma unroll
    for (int off = 1; off < 16; off <<= 1) v += __shfl_xor(v, off);
    return v;
}

// ---- rowsum: row_sum (half) + ||row_sum||^2 (f32) ----
__global__ __launch_bounds__(512) void rowsum_kernel(
    const float* __restrict__ scene_emb,   // [5001, 64]
    const int*   __restrict__ csp,         // [N, 10]
    h4*          __restrict__ rowsum_h,    // [N, 16] h4
    float*       __restrict__ nrm)         // [N]
{
    const int tid  = threadIdx.x;
    const int lane = tid & 63;
    const int l16  = lane & 15;
    const int row  = blockIdx.x * 32 + (tid >> 6) * 4 + (lane >> 4);

    int sidx = csp[row * MAX_SCENES + (l16 < 9 ? l16 : 9)];
    const f4* scene4 = (const f4*)scene_emb;

    f4 a[MAX_SCENES];
#pragma unroll
    for (int k = 0; k < MAX_SCENES; ++k)
        a[k] = scene4[__shfl(sidx, k, 16) * 16 + l16];   // broadcast id, 256B/group, all in flight

    f4 s = {0.f, 0.f, 0.f, 0.f};
#pragma unroll
    for (int k = 0; k < MAX_SCENES; ++k) {
        s.x += a[k].x; s.y += a[k].y; s.z += a[k].z; s.w += a[k].w;
    }
    float n2 = reduce16(s.x * s.x + s.y * s.y + s.z * s.z + s.w * s.w);

    h4 hv = {(_Float16)s.x, (_Float16)s.y, (_Float16)s.z, (_Float16)s.w};
    rowsum_h[row * 16 + l16] = hv;
    if (l16 == 0) nrm[row] = n2;
}

// ---- main: sim softmax + aggregation + dense(fp16 dot2) + ELU ----
__global__ __launch_bounds__(512) void main_kernel(
    const h4*    __restrict__ rowsum_h,    // [N,16] h4
    const float* __restrict__ nrm,         // [N]
    const h4*    __restrict__ cate_h,      // [N,16] h4
    const int*   __restrict__ ccp,         // [N,16]
    const unsigned int* __restrict__ Wt2g, // [64 k2][64 d] half2
    const float* __restrict__ bias,        // [64]
    float*       __restrict__ out)         // [N,64]
{
    __shared__ unsigned int Wt2[64 * 64];  // 16384 B
    __shared__ h4 hsh[32][33];             // 8448 B; h[row][128 halves], padded

    const int tid  = threadIdx.x;
    const int lane = tid & 63;
    const int l16  = lane & 15;
    const int rl   = (tid >> 6) * 4 + (lane >> 4);
    const int row  = blockIdx.x * 32 + rl;

    {   // conflict-free straight copy, 1024 uint4
        const uint4* src = (const uint4*)Wt2g;
        uint4* dst = (uint4*)Wt2;
        dst[tid] = src[tid];
        dst[tid + 512] = src[tid + 512];
    }

    // ids: lane l16 holds neighbor l16
    int nidx = ccp[row * MAX_NGH + l16];
    int idx[1 + MAX_NGH];
    idx[0] = row;
#pragma unroll
    for (int j = 1; j < 1 + MAX_NGH; ++j) idx[j] = __shfl(nidx, j - 1, 16);

    // batch all rowsum gathers (128B/group each, 17 in flight)
    h4 rv[1 + MAX_NGH];
#pragma unroll
    for (int j = 0; j < 1 + MAX_NGH; ++j) rv[j] = rowsum_h[idx[j] * 16 + l16];

    float nrm_n = nrm[nidx];               // scattered 4B, 400KB table = L2-hot
    float ns    = nrm[row] + EPSF;
    float ns_inv = FRCP(ns);

    f4 s = {(float)rv[0].x, (float)rv[0].y, (float)rv[0].z, (float)rv[0].w};

    float miu[1 + MAX_NGH];
    float summiu = 0.f;
#pragma unroll
    for (int j = 0; j < 1 + MAX_NGH; ++j) {
        f4 r = {(float)rv[j].x, (float)rv[j].y, (float)rv[j].z, (float)rv[j].w};
        float dot = fmaf(s.x, r.x, fmaf(s.y, r.y, fmaf(s.z, r.z, s.w * r.w)));
#pragma unroll
        for (int off = 1; off < 16; off <<= 1) dot += __shfl_xor(dot, off);
        float rr = (j == 0) ? (ns - EPSF) : __shfl(nrm_n, j - 1, 16);
        bool m = idx[j] < (NUM_CATES - 1);
        float mu = m ? __expf(dot * ns_inv * FRCP(rr + EPSF)) : 0.f;
        miu[j] = mu;
        summiu += mu;
    }

    // batch all cate gathers
    h4 cv[1 + MAX_NGH];
#pragma unroll
    for (int j = 0; j < 1 + MAX_NGH; ++j) cv[j] = cate_h[idx[j] * 16 + l16];

    const float inv = FRCP(summiu + EPSF);
    f4 agg = {0.f, 0.f, 0.f, 0.f};
#pragma unroll
    for (int j = 0; j < 1 + MAX_NGH; ++j) {
        float w = miu[j] * inv;
        agg.x = fmaf(w, (float)cv[j].x, agg.x);
        agg.y = fmaf(w, (float)cv[j].y, agg.y);
        agg.z = fmaf(w, (float)cv[j].z, agg.z);
        agg.w = fmaf(w, (float)cv[j].w, agg.w);
    }

    // h = [s | agg] as halves
    hsh[rl][l16] = rv[0];
    h4 ah = {(_Float16)agg.x, (_Float16)agg.y, (_Float16)agg.z, (_Float16)agg.w};
    hsh[rl][16 + l16] = ah;
    __syncthreads();

    // out[d] = elu( sum_k W[d][k] h[k] + b[d] ), lane owns d = 4*l16..+3, v_dot2 f32-acc
    f4 acc = ((const f4*)bias)[l16];
#pragma unroll 8
    for (int k4 = 0; k4 < 32; ++k4) {
        h4 hv = hsh[rl][k4];                                  // group-uniform broadcast
        h2 ha = {hv.x, hv.y}, hb = {hv.z, hv.w};
        const uint4 wA = *(const uint4*)&Wt2[(2 * k4) * 64 + 4 * l16];
        const uint4 wB = *(const uint4*)&Wt2[(2 * k4 + 1) * 64 + 4 * l16];
        acc.x = FDOT2(bc2(wA.x), ha, acc.x);
        acc.y = FDOT2(bc2(wA.y), ha, acc.y);
        acc.z = FDOT2(bc2(wA.z), ha, acc.z);
        acc.w = FDOT2(bc2(wA.w), ha, acc.w);
        acc.x = FDOT2(bc2(wB.x), hb, acc.x);
        acc.y = FDOT2(bc2(wB.y), hb, acc.y);
        acc.z = FDOT2(bc2(wB.z), hb, acc.z);
        acc.w = FDOT2(bc2(wB.w), hb, acc.w);
    }

    f4 o;
    o.x = acc.x > 0.f ? acc.x : (__expf(acc.x) - 1.f);
    o.y = acc.y > 0.f ? acc.y : (__expf(acc.y) - 1.f);
    o.z = acc.z > 0.f ? acc.z : (__expf(acc.z) - 1.f);
    o.w = acc.w > 0.f ? acc.w : (__expf(acc.w) - 1.f);
    ((f4*)out)[row * 16 + l16] = o;
}

extern "C" void kernel_launch(void* const* d_in, const int* in_sizes, int n_in,
                              void* d_out, int out_size, void* d_ws, size_t ws_size,
                              hipStream_t stream) {
    const float* cate_emb  = (const float*)d_in[1];
    const float* scene_emb = (const float*)d_in[2];
    const int*   csp       = (const int*)d_in[3];
    const int*   ccp       = (const int*)d_in[4];
    const float* W         = (const float*)d_in[5];
    const float* bias      = (const float*)d_in[6];

    // ws layout (bytes): Wt2g 16384 | rowsum_h 12.8MB | nrm 400KB | cate_h 12.8MB  (~26 MB)
    char* ws = (char*)d_ws;
    unsigned int* Wt2g  = (unsigned int*)ws;
    h4*    rowsum_h     = (h4*)(ws + 16384);
    float* nrm          = (float*)(ws + 16384 + 12800000);
    h4*    cate_h       = (h4*)(ws + 16384 + 12800000 + 400000);
    float* out          = (float*)d_out;

    prep_kernel  <<<3126, 512, 0, stream>>>(W, cate_emb, Wt2g, cate_h);
    rowsum_kernel<<<NROWS / 32, 512, 0, stream>>>(scene_emb, csp, rowsum_h, nrm);
    main_kernel  <<<NROWS / 32, 512, 0, stream>>>(rowsum_h, nrm, cate_h, ccp, Wt2g, bias, out);
}